// Round 1
// 325.061 us; speedup vs baseline: 1.0016x; 1.0016x over previous
//
#include <hip/hip_runtime.h>
#include <stdint.h>

#define NUM_BONES  50
#define FEAT       150
#define FPT        8                          // frames per tile
#define THREADS    256
#define TILE_FLOATS (FPT * FEAT)              // 1200 floats = 4800 B = 300 float4
#define TOTAL_FRAMES (64 * 4096)
#define TOTAL_TILES  (TOTAL_FRAMES / FPT)     // 32768
#define GRID_BLOCKS  2048                     // 8 blocks/CU (LDS 19.2KB/block)
#define TILES_PER_BLOCK (TOTAL_TILES / GRID_BLOCKS)   // 16
#define NTASK      (FPT * NUM_BONES)          // 400 bone-tasks per tile

// 50-bone skeleton (body + two 21-bone hands + pad bone (0,2))
__device__ __constant__ int c_ba[NUM_BONES] = {
    0, 1, 2, 3, 1, 5, 6,
    7, 8, 9, 10, 11, 8, 13, 14, 15, 8, 17, 18, 19,
    8, 21, 22, 23, 8, 25, 26, 27,
    4, 29, 30, 31, 32, 29, 34, 35, 36, 29, 38, 39, 40,
    29, 42, 43, 44, 29, 46, 47, 48,
    0
};
__device__ __constant__ int c_bb[NUM_BONES] = {
    1, 2, 3, 4, 5, 6, 7,
    8, 9, 10, 11, 12, 13, 14, 15, 16, 17, 18, 19, 20,
    21, 22, 23, 24, 25, 26, 27, 28,
    29, 30, 31, 32, 33, 34, 35, 36, 37, 38, 39, 40, 41,
    42, 43, 44, 45, 46, 47, 48, 49,
    2
};

#define AS1 __attribute__((address_space(1)))
#define AS3 __attribute__((address_space(3)))

// DMA one float4 per active lane: global (per-lane addr) -> LDS (wave-uniform
// base + lane*16). LDS ptr via uintptr_t truncation (low 32b of flat LDS
// address == LDS offset; CK's amd_direct_load pattern).
__device__ __forceinline__ void gload16(const float* g, float* l)
{
    __builtin_amdgcn_global_load_lds((AS1 unsigned int*)(uintptr_t)g,
                                     (AS3 unsigned int*)(uintptr_t)l,
                                     16, 0, 0);
}

// Stage one tensor's tile (300 float4) into LDS.
// Per wave: 1 full issue (64 lanes, f4 idx = tid) + 1 tail issue (11 lanes,
// f4 idx = 256 + 11*wv + ln). Exactly 2 vmcnt events per wave per tensor,
// uniform across waves (tail branch taken by every wave).
__device__ __forceinline__ void stage_tile(const float* __restrict__ src,
                                           float* lds, int wv, int ln, int tile)
{
    const float* base = src + (size_t)tile * TILE_FLOATS;
    gload16(base + ((wv * 64 + ln) << 2), lds + wv * 256);
    if (ln < 11)
        gload16(base + ((256 + wv * 11 + ln) << 2), lds + 1024 + wv * 44);
}

// One bone-task: frame f, bone b. ja/jb/ob are precomputed word offsets
// (f*150 + 3*joint). Raw p,t live in LDS; mask applied on read
// (pm = t!=0 ? p : 0; tm == t identically). The ob-triple also carries this
// task's share of the L1 term: {3b,3b+1,3b+2} tiles 0..149 exactly once.
__device__ __forceinline__ void bone_task(const float* __restrict__ P,
                                          const float* __restrict__ T,
                                          int ja, int jb, int ob,
                                          float& l1, float& mse)
{
    float pax = P[ja], pay = P[ja + 1], paz = P[ja + 2];
    float pbx = P[jb], pby = P[jb + 1], pbz = P[jb + 2];
    float tax = T[ja], tay = T[ja + 1], taz = T[ja + 2];
    float tbx = T[jb], tby = T[jb + 1], tbz = T[jb + 2];
    float pox = P[ob], poy = P[ob + 1], poz = P[ob + 2];
    float tox = T[ob], toy = T[ob + 1], toz = T[ob + 2];

    pax = (tax != 0.0f) ? pax : 0.0f;
    pay = (tay != 0.0f) ? pay : 0.0f;
    paz = (taz != 0.0f) ? paz : 0.0f;
    pbx = (tbx != 0.0f) ? pbx : 0.0f;
    pby = (tby != 0.0f) ? pby : 0.0f;
    pbz = (tbz != 0.0f) ? pbz : 0.0f;
    pox = (tox != 0.0f) ? pox : 0.0f;
    poy = (toy != 0.0f) ? poy : 0.0f;
    poz = (toz != 0.0f) ? poz : 0.0f;

    l1 += fabsf(pox - tox) + fabsf(poy - toy) + fabsf(poz - toz);

    float dpx = pax - pbx, dpy = pay - pby, dpz = paz - pbz;
    float dtx = tax - tbx, dty = tay - tby, dtz = taz - tbz;
    float lp2 = dpx * dpx + dpy * dpy + dpz * dpz;
    float lt2 = dtx * dtx + dty * dty + dtz * dtz;
    // dir = diff * rsqrt(|diff|^2); exact 0 when diff == 0.
    // rsq approx err ~1e-7 vs 2.4e-2 tolerance (validated, absmax 0.0).
    float ip = (lp2 > 0.0f) ? __builtin_amdgcn_rsqf(lp2) : 0.0f;
    float it = (lt2 > 0.0f) ? __builtin_amdgcn_rsqf(lt2) : 0.0f;
    float e0 = dpx * ip - dtx * it;
    float e1 = dpy * ip - dty * it;
    float e2 = dpz * ip - dtz * it;
    mse += (tox != 0.0f) ? e0 * e0 : 0.0f;
    mse += (toy != 0.0f) ? e1 * e1 : 0.0f;
    mse += (toz != 0.0f) ? e2 * e2 : 0.0f;
}

__global__ __launch_bounds__(THREADS)
void loss_main(const float* __restrict__ preds,
               const float* __restrict__ targets,
               double* __restrict__ part0,
               double* __restrict__ part1)
{
    // Double-buffered DMA tiles: 2 x 2 x 4800 B = 19200 B -> 8 blocks/CU.
    __shared__ float s_p[2][TILE_FLOATS];
    __shared__ float s_t[2][TILE_FLOATS];

    const int tid = threadIdx.x;
    const int wv = tid >> 6;
    const int ln = tid & 63;

    // Task offsets are fixed per (tid, k): task i = tid + 256k, f=i&7, b=i>>3.
    // Precompute once (one divergent constant-mem gather, outside the loop).
    int ja0, jb0, ob0, ja1, jb1, ob1;
    {
        int f = tid & 7, b = tid >> 3;           // k=0: i<256<400, always valid
        ja0 = f * FEAT + 3 * c_ba[b];
        jb0 = f * FEAT + 3 * c_bb[b];
        ob0 = f * FEAT + 3 * b;
        int i1 = tid + THREADS;                  // k=1: valid iff tid < 144
        int ii = (i1 < NTASK) ? i1 : 0;
        f = ii & 7; b = ii >> 3;
        ja1 = f * FEAT + 3 * c_ba[b];
        jb1 = f * FEAT + 3 * c_bb[b];
        ob1 = f * FEAT + 3 * b;
    }

    float l1 = 0.0f, mse = 0.0f;

    // Prologue: DMA tile 0 into buffer 0 (4 vmcnt events per wave).
    stage_tile(preds,   s_p[0], wv, ln, (int)blockIdx.x);
    stage_tile(targets, s_t[0], wv, ln, (int)blockIdx.x);

#pragma unroll 1
    for (int j = 0; j < TILES_PER_BLOCK; ++j) {
        const int bs = j & 1;
        // Issue next tile's DMA (into the buffer last read 2 barriers ago),
        // then wait only for the CURRENT tile (counted vmcnt, never drain).
        if (j + 1 < TILES_PER_BLOCK) {
            const int tn = (int)blockIdx.x + (j + 1) * GRID_BLOCKS;
            stage_tile(preds,   s_p[bs ^ 1], wv, ln, tn);
            stage_tile(targets, s_t[bs ^ 1], wv, ln, tn);
            asm volatile("s_waitcnt vmcnt(4)" ::: "memory");
        } else {
            asm volatile("s_waitcnt vmcnt(0)" ::: "memory");
        }
        __builtin_amdgcn_sched_barrier(0);
        __builtin_amdgcn_s_barrier();        // all waves' slices of tile j landed
        __builtin_amdgcn_sched_barrier(0);   // keep ds_reads below the barrier

        const float* P = s_p[bs];
        const float* T = s_t[bs];
        bone_task(P, T, ja0, jb0, ob0, l1, mse);
        if (tid < (NTASK - THREADS))
            bone_task(P, T, ja1, jb1, ob1, l1, mse);

        __builtin_amdgcn_sched_barrier(0);
        __builtin_amdgcn_s_barrier();        // all reads done before next overwrite
    }

    // ---- Block reduction (double), no global atomics ----
    double v0 = (double)l1;
    double v1 = (double)mse;
    for (int off = 32; off > 0; off >>= 1) {
        v0 += __shfl_down(v0, off, 64);
        v1 += __shfl_down(v1, off, 64);
    }
    __shared__ double s_red0[THREADS / 64];
    __shared__ double s_red1[THREADS / 64];
    if (ln == 0) { s_red0[wv] = v0; s_red1[wv] = v1; }
    __syncthreads();
    if (tid == 0) {
        part0[blockIdx.x] = s_red0[0] + s_red0[1] + s_red0[2] + s_red0[3];
        part1[blockIdx.x] = s_red1[0] + s_red1[1] + s_red1[2] + s_red1[3];
    }
}

__global__ __launch_bounds__(THREADS)
void loss_final(const double* __restrict__ part0,
                const double* __restrict__ part1,
                float* __restrict__ out)
{
    const int tid = threadIdx.x;
    double a = 0.0, b = 0.0;
    for (int i = tid; i < GRID_BLOCKS; i += THREADS) {
        a += part0[i];
        b += part1[i];
    }
    for (int off = 32; off > 0; off >>= 1) {
        a += __shfl_down(a, off, 64);
        b += __shfl_down(b, off, 64);
    }
    __shared__ double s0[THREADS / 64];
    __shared__ double s1[THREADS / 64];
    const int wave = tid >> 6;
    const int lane = tid & 63;
    if (lane == 0) { s0[wave] = a; s1[wave] = b; }
    __syncthreads();
    if (tid == 0) {
        double sa = s0[0] + s0[1] + s0[2] + s0[3];
        double sb = s1[0] + s1[1] + s1[2] + s1[3];
        const double N = 64.0 * 4096.0 * 150.0;  // both means over B*T*150
        out[0] = (float)(sa / N + 0.1 * (sb / N));
    }
}

extern "C" void kernel_launch(void* const* d_in, const int* in_sizes, int n_in,
                              void* d_out, int out_size, void* d_ws, size_t ws_size,
                              hipStream_t stream)
{
    (void)in_sizes; (void)n_in; (void)out_size; (void)ws_size;
    const float* preds   = (const float*)d_in[0];
    const float* targets = (const float*)d_in[1];
    double* part0 = (double*)d_ws;
    double* part1 = part0 + GRID_BLOCKS;   // 32 KB total in d_ws

    loss_main<<<GRID_BLOCKS, THREADS, 0, stream>>>(preds, targets, part0, part1);
    loss_final<<<1, THREADS, 0, stream>>>(part0, part1, (float*)d_out);
}